// Round 2
// baseline (260.862 us; speedup 1.0000x reference)
//
#include <hip/hip_runtime.h>
#include <cstdint>
#include <cstddef>

#define NB 64
#define NS 2048
#define NH 512
#define NA 512

#define BM 64
#define BK 32

typedef __attribute__((ext_vector_type(8))) short short8;
typedef __attribute__((ext_vector_type(4))) float f32x4;

__device__ inline short f2bf(float f) {
    union { float f; uint32_t u; } v; v.f = f;
    uint32_t u = v.u;
    uint32_t r = (u + 0x7fffu + ((u >> 16) & 1u)) >> 16;
    return (short)r;
}

__device__ inline uint32_t cvtpk_bf16(float lo, float hi) {
    uint32_t r;
    asm("v_cvt_pk_bf16_f32 %0, %1, %2" : "=v"(r) : "v"(lo), "v"(hi));
    return r;
}

// ---------------- kernel 1a: dec_p[b][a] = dec[b]·W_dec[a] + b_dec[a] + b_enc[a]
__global__ __launch_bounds__(256) void k_decp(const float* __restrict__ dec,
                                              const float* __restrict__ Wd,
                                              const float* __restrict__ bd,
                                              const float* __restrict__ be,
                                              float* __restrict__ dp) {
    int b = blockIdx.x;
    __shared__ float dl[NH];
    for (int i = threadIdx.x; i < NH; i += 256) dl[i] = dec[b * NH + i];
    __syncthreads();
    for (int a = threadIdx.x; a < NA; a += 256) {
        const float4* wr = (const float4*)(Wd + (size_t)a * NH);
        float acc = 0.f;
#pragma unroll 8
        for (int h4 = 0; h4 < NH / 4; ++h4) {
            float4 w = wr[h4];
            acc += dl[h4*4+0]*w.x + dl[h4*4+1]*w.y + dl[h4*4+2]*w.z + dl[h4*4+3]*w.w;
        }
        dp[b * NA + a] = acc + bd[a] + be[a];
    }
}

// ---------------- kernel 1b: pack W_enc fp32 -> bf16, K-tiled (linear, no swizzle)
// layout: wsw[kt][a][slot][8 bf16], kt = 0..15 (32-k tiles), slot = k/8 within tile
__global__ __launch_bounds__(256) void k_packw(const float* __restrict__ We,
                                               short* __restrict__ wsw) {
    int t = blockIdx.x * 256 + threadIdx.x;      // 0..32767
    int slot = t & 3;
    int a = (t >> 2) & (NA - 1);
    int kt = t >> 11;                             // 0..15
    const float* src = We + (size_t)a * NH + kt * 32 + slot * 8;
    short* dst = wsw + (((size_t)kt * NA + a) * 4 + slot) * 8;
    short8 o;
#pragma unroll
    for (int j = 0; j < 8; ++j) o[j] = f2bf(src[j]);
    *(short8*)dst = o;
}

// ---------------- kernel 2: fused enc proj + tanh + dot(V) + exp + ctx partial
// grid: (B*S)/BM = 2048 blocks, 256 threads (4 waves). Wave w covers a in [w*128, w*128+128).
// Barrier-free K-loop: A fragments straight from enc (fp32->bf16 via cvt_pk),
// B fragments straight from L2-resident packed W. No LDS staging at all.
__global__ __launch_bounds__(256, 2) void k_fused(const float* __restrict__ enc,
                                                  const short* __restrict__ wsw,
                                                  const float* __restrict__ dp,
                                                  const float* __restrict__ V,
                                                  float* __restrict__ pbuf,
                                                  float* __restrict__ ctxp) {
    __shared__ float sbuf[4][BM];   // per-wave score partials
    __shared__ float pl[BM];        // exp(score) broadcast
    __shared__ float sb2[4][NH];    // per-wave ctx partials (8 KB)

    const int tid = threadIdx.x;
    const int w = tid >> 6;            // wave 0..3
    const int l = tid & 63;
    const int lrow = l & 15;
    const int lg = l >> 4;
    const int row0 = blockIdx.x * BM;  // flat row in [0, B*S)
    const int b = row0 / NS;

    // per-lane bases
    const float* ap = enc + (size_t)(row0 + lrow) * NH + lg * 8;   // A: row0+fm*16+lrow, k = kt*32+lg*8
    const short* bp = wsw + ((size_t)(w * 128 + lrow) * 4 + lg) * 8; // B: a = w*128+fn*16+lrow

    f32x4 acc[4][8];
#pragma unroll
    for (int i = 0; i < 4; ++i)
#pragma unroll
        for (int j = 0; j < 8; ++j) acc[i][j] = (f32x4){0.f, 0.f, 0.f, 0.f};

#pragma unroll 2
    for (int kt = 0; kt < NH / BK; ++kt) {
        short8 bfr[8];
#pragma unroll
        for (int fn = 0; fn < 8; ++fn)
            bfr[fn] = *(const short8*)(bp + (size_t)kt * 16384 + fn * 512);

        short8 af[4];
#pragma unroll
        for (int fm = 0; fm < 4; ++fm) {
            const float* a_ = ap + (size_t)kt * 32 + fm * (16 * NH);
            f32x4 a0 = *(const f32x4*)(a_);
            f32x4 a1 = *(const f32x4*)(a_ + 4);
            union { short8 s8; uint32_t u[4]; } uu;
            uu.u[0] = cvtpk_bf16(a0[0], a0[1]);
            uu.u[1] = cvtpk_bf16(a0[2], a0[3]);
            uu.u[2] = cvtpk_bf16(a1[0], a1[1]);
            uu.u[3] = cvtpk_bf16(a1[2], a1[3]);
            af[fm] = uu.s8;
        }

#pragma unroll
        for (int fm = 0; fm < 4; ++fm)
#pragma unroll
            for (int fn = 0; fn < 8; ++fn)
                acc[fm][fn] = __builtin_amdgcn_mfma_f32_16x16x32_bf16(af[fm], bfr[fn], acc[fm][fn], 0, 0, 0);
    }

    // ---- epilogue 1: tanh(acc + dec_p) * V, reduce over a -> scores
    float dpl[8], vl[8];
#pragma unroll
    for (int fn = 0; fn < 8; ++fn) {
        int a = w * 128 + fn * 16 + lrow;
        dpl[fn] = dp[b * NA + a];
        vl[fn] = V[a];
    }
    float ps[4][4];
#pragma unroll
    for (int fm = 0; fm < 4; ++fm)
#pragma unroll
        for (int i = 0; i < 4; ++i) ps[fm][i] = 0.f;

#pragma unroll
    for (int fm = 0; fm < 4; ++fm)
#pragma unroll
        for (int fn = 0; fn < 8; ++fn)
#pragma unroll
            for (int i = 0; i < 4; ++i) {
                float x = acc[fm][fn][i] + dpl[fn];
                float u = exp2f(x * 2.885390082f);           // tanh via exp2
                float th = 1.f - 2.f * __builtin_amdgcn_rcpf(u + 1.f);
                ps[fm][i] += th * vl[fn];
            }

#pragma unroll
    for (int fm = 0; fm < 4; ++fm)
#pragma unroll
        for (int i = 0; i < 4; ++i) {
            float v = ps[fm][i];
            v += __shfl_xor(v, 1);
            v += __shfl_xor(v, 2);
            v += __shfl_xor(v, 4);
            v += __shfl_xor(v, 8);
            if (lrow == 0) sbuf[w][fm * 16 + lg * 4 + i] = v;
        }
    __syncthreads();

    // ---- epilogue 2: p = exp(score) (no max: |score| <= ~11, fp32-safe; b_v cancels)
    if (tid < BM) {
        float s = sbuf[0][tid] + sbuf[1][tid] + sbuf[2][tid] + sbuf[3][tid];
        float p = exp2f(s * 1.4426950408889634f);
        pl[tid] = p;
        pbuf[row0 + tid] = p;
    }
    __syncthreads();

    // ---- epilogue 3: ctx partial = sum_s p_s * enc[s][:]
    // wave w owns s in [w*16, w*16+16); lane l owns h = l*8 .. l*8+8
    f32x4 c0 = (f32x4){0.f, 0.f, 0.f, 0.f};
    f32x4 c1 = (f32x4){0.f, 0.f, 0.f, 0.f};
    const float* erow = enc + (size_t)(row0 + w * 16) * NH + l * 8;
#pragma unroll 4
    for (int s16 = 0; s16 < 16; ++s16) {
        float pw = pl[w * 16 + s16];
        f32x4 e0 = *(const f32x4*)(erow);
        f32x4 e1 = *(const f32x4*)(erow + 4);
        c0 += pw * e0;
        c1 += pw * e1;
        erow += NH;
    }
    *(f32x4*)(&sb2[w][l * 8]) = c0;
    *(f32x4*)(&sb2[w][l * 8 + 4]) = c1;
    __syncthreads();

    // 256 threads x 2 h each: sum 4 waves, write partial
    {
        int h2 = tid * 2;
        float r0 = sb2[0][h2] + sb2[1][h2] + sb2[2][h2] + sb2[3][h2];
        float r1 = sb2[0][h2+1] + sb2[1][h2+1] + sb2[2][h2+1] + sb2[3][h2+1];
        float2* dst = (float2*)(ctxp + (size_t)blockIdx.x * NH + h2);
        *dst = make_float2(r0, r1);
    }
}

// ---------------- kernel 3: combine partials -> out = [ctx | dec]
// grid: B blocks, 256 threads
__global__ __launch_bounds__(256) void k_combine(const float* __restrict__ ctxp,
                                                 const float* __restrict__ pbuf,
                                                 const float* __restrict__ dec,
                                                 float* __restrict__ out) {
    int b = blockIdx.x;
    int tid = threadIdx.x;
    int l = tid & 63;
    int w = tid >> 6;
    __shared__ float red[4];
    __shared__ float stot;

    // denominator: sum of 2048 p values
    const f32x4* pv = (const f32x4*)(pbuf + (size_t)b * NS);
    f32x4 v0 = pv[tid * 2];
    f32x4 v1 = pv[tid * 2 + 1];
    float s = v0[0]+v0[1]+v0[2]+v0[3]+v1[0]+v1[1]+v1[2]+v1[3];
#pragma unroll
    for (int off = 1; off < 64; off <<= 1) s += __shfl_xor(s, off);
    if (l == 0) red[w] = s;
    __syncthreads();
    if (tid == 0) stot = red[0] + red[1] + red[2] + red[3];
    __syncthreads();
    float inv = 1.f / stot;

    // numerator: sum of 32 partials, 2 h per thread
    int h2 = tid * 2;
    float a0 = 0.f, a1 = 0.f;
#pragma unroll 8
    for (int i = 0; i < NS / BM; ++i) {
        const float2 c = *(const float2*)(ctxp + ((size_t)b * (NS / BM) + i) * NH + h2);
        a0 += c.x;
        a1 += c.y;
    }
    *(float2*)(out + (size_t)b * 1024 + h2) = make_float2(a0 * inv, a1 * inv);
    // pass-through dec
    const float2 dv = *(const float2*)(dec + (size_t)b * NH + h2);
    *(float2*)(out + (size_t)b * 1024 + NH + h2) = dv;
}

extern "C" void kernel_launch(void* const* d_in, const int* in_sizes, int n_in,
                              void* d_out, int out_size, void* d_ws, size_t ws_size,
                              hipStream_t stream) {
    (void)in_sizes; (void)n_in; (void)out_size; (void)ws_size;
    const float* dec = (const float*)d_in[0];
    const float* enc = (const float*)d_in[1];
    const float* Wd  = (const float*)d_in[2];
    const float* bd  = (const float*)d_in[3];
    const float* We  = (const float*)d_in[4];
    const float* be  = (const float*)d_in[5];
    const float* V   = (const float*)d_in[6];
    // d_in[7] (b_v) unused: cancels in softmax
    float* out = (float*)d_out;

    char* ws = (char*)d_ws;
    short* wsw    = (short*)ws;                         // 512 KB packed bf16 W
    float* dpb    = (float*)(ws + (512 << 10));         // 128 KB dec_p
    float* pbuf   = (float*)(ws + (640 << 10));         // 512 KB exp(scores)
    float* ctxp   = (float*)(ws + (1152 << 10));        // 4 MB ctx partials

    k_decp<<<dim3(NB), dim3(256), 0, stream>>>(dec, Wd, bd, be, dpb);
    k_packw<<<dim3(128), dim3(256), 0, stream>>>(We, wsw);
    k_fused<<<dim3((NB * NS) / BM), dim3(256), 0, stream>>>(enc, wsw, dpb, V, pbuf, ctxp);
    k_combine<<<dim3(NB), dim3(256), 0, stream>>>(ctxp, pbuf, dec, out);
}

// Round 3
// 166.261 us; speedup vs baseline: 1.5690x; 1.5690x over previous
//
#include <hip/hip_runtime.h>
#include <cstdint>
#include <cstddef>

#define NB 64
#define NS 2048
#define NH 512
#define NA 512

#define BM 64
#define BK 32

typedef __attribute__((ext_vector_type(8))) short short8;
typedef __attribute__((ext_vector_type(4))) float f32x4;

__device__ inline short f2bf(float f) {
    union { float f; uint32_t u; } v; v.f = f;
    uint32_t u = v.u;
    uint32_t r = (u + 0x7fffu + ((u >> 16) & 1u)) >> 16;
    return (short)r;
}

__device__ inline uint32_t cvtpk_bf16(float lo, float hi) {
    uint32_t r;
    asm("v_cvt_pk_bf16_f32 %0, %1, %2" : "=v"(r) : "v"(lo), "v"(hi));
    return r;
}

// ---------------- kernel 1a: dec_p[b][a] = dec[b]·W_dec[a] + b_dec[a] + b_enc[a]
__global__ __launch_bounds__(256) void k_decp(const float* __restrict__ dec,
                                              const float* __restrict__ Wd,
                                              const float* __restrict__ bd,
                                              const float* __restrict__ be,
                                              float* __restrict__ dp) {
    int b = blockIdx.x;
    __shared__ float dl[NH];
    for (int i = threadIdx.x; i < NH; i += 256) dl[i] = dec[b * NH + i];
    __syncthreads();
    for (int a = threadIdx.x; a < NA; a += 256) {
        const float4* wr = (const float4*)(Wd + (size_t)a * NH);
        float acc = 0.f;
#pragma unroll 8
        for (int h4 = 0; h4 < NH / 4; ++h4) {
            float4 w = wr[h4];
            acc += dl[h4*4+0]*w.x + dl[h4*4+1]*w.y + dl[h4*4+2]*w.z + dl[h4*4+3]*w.w;
        }
        dp[b * NA + a] = acc + bd[a] + be[a];
    }
}

// ---------------- kernel 1b: pack W_enc fp32 -> bf16, K-tiled + slot-swizzled
// layout: wsw[kt][a][slot ^ ((a>>1)&3)][8 bf16]
__global__ __launch_bounds__(256) void k_packw(const float* __restrict__ We,
                                               short* __restrict__ wsw) {
    int t = blockIdx.x * 256 + threadIdx.x;      // 0..32767
    int slot = t & 3;
    int a = (t >> 2) & (NA - 1);
    int kt = t >> 11;                             // 0..15
    const float* src = We + (size_t)a * NH + kt * 32 + slot * 8;
    int dslot = slot ^ ((a >> 1) & 3);
    short* dst = wsw + (((size_t)kt * NA + a) * 4 + dslot) * 8;
    short8 o;
#pragma unroll
    for (int j = 0; j < 8; ++j) o[j] = f2bf(src[j]);
    *(short8*)dst = o;
}

// ---------------- kernel 2: fused enc proj + tanh + dot(V) + exp + ctx partial
// 2048 blocks x 256 thr (4 waves). 2-phase double-buffered K-loop:
//   stage(kt+1) issued BEFORE MFMA(kt); one barrier per K-step.
// LDS: W dbuf 2x32KB (global_load_lds from pre-swizzled pack), A dbuf 2x4KB
// (reg-staged fp32->bf16 cvt_pk, k-group-major swizzled layout). Epilogue overlays.
__global__ __launch_bounds__(256, 2) void k_fused(const float* __restrict__ enc,
                                                  const short* __restrict__ wsw,
                                                  const float* __restrict__ dp,
                                                  const float* __restrict__ V,
                                                  float* __restrict__ pbuf,
                                                  float* __restrict__ ctxp) {
    __shared__ __align__(16) char smem[73728];   // 2x32KB W + 2x4KB A; epilogue overlays

    const int tid = threadIdx.x;
    const int w = tid >> 6;
    const int l = tid & 63;
    const int lrow = l & 15;
    const int lg = l >> 4;
    const int row0 = blockIdx.x * BM;
    const int b = row0 >> 11;          // row0 / NS

    // A staging mapping: thread -> (row sa, k-group qa); LDS layout [qa][sa^(qa<<2)] 16B units
    const int sa = tid >> 2;
    const int qa = tid & 3;
    const float* encs = enc + (size_t)(row0 + sa) * NH + qa * 8;
    const int aw_byte = (qa * 64 + (sa ^ (qa << 2))) * 16;

    const char* wsrc = (const char*)wsw;

    // fragment read byte offsets (constant per lane)
    const int wfrag = ((w * 128 + lrow) * 4 + (lg ^ ((lrow >> 1) & 3))) * 16;
    const int afrag = (lg * 64 + (lrow ^ (lg << 2))) * 16;   // + fm*256

    f32x4 acc[4][8];
#pragma unroll
    for (int i = 0; i < 4; ++i)
#pragma unroll
        for (int j = 0; j < 8; ++j) acc[i][j] = (f32x4){0.f, 0.f, 0.f, 0.f};

    // ---- prologue: stage kt=0 into buf0
    {
#pragma unroll
        for (int r = 0; r < 8; ++r) {
            int blk = r * 4 + w;
            __builtin_amdgcn_global_load_lds(
                (const __attribute__((address_space(1))) void*)(wsrc + ((size_t)blk * 64 + l) * 16),
                (__attribute__((address_space(3))) void*)(smem + blk * 1024), 16, 0, 0);
        }
        f32x4 a0 = *(const f32x4*)(encs);
        f32x4 a1 = *(const f32x4*)(encs + 4);
        union { short8 s8; uint32_t u[4]; } uu;
        uu.u[0] = cvtpk_bf16(a0[0], a0[1]);
        uu.u[1] = cvtpk_bf16(a0[2], a0[3]);
        uu.u[2] = cvtpk_bf16(a1[0], a1[1]);
        uu.u[3] = cvtpk_bf16(a1[2], a1[3]);
        *(short8*)(smem + 65536 + aw_byte) = uu.s8;
    }
    __syncthreads();

    // ---- 2-phase K-loop
    for (int kt = 0; kt < 16; ++kt) {
        const int cur = kt & 1;
        char* Wc = smem + cur * 32768;
        char* Ac = smem + 65536 + cur * 4096;
        char* Wn = smem + (cur ^ 1) * 32768;
        char* An = smem + 65536 + (cur ^ 1) * 4096;

        // issue next-tile staging (loads in flight across the MFMA block)
        f32x4 a0, a1;
        if (kt < 15) {
            const float* s = encs + (kt + 1) * BK;
            a0 = *(const f32x4*)(s);
            a1 = *(const f32x4*)(s + 4);
#pragma unroll
            for (int r = 0; r < 8; ++r) {
                int blk = r * 4 + w;
                __builtin_amdgcn_global_load_lds(
                    (const __attribute__((address_space(1))) void*)(wsrc + ((size_t)(kt + 1) * 32768 + ((size_t)blk * 64 + l) * 16)),
                    (__attribute__((address_space(3))) void*)(Wn + blk * 1024), 16, 0, 0);
            }
        }

        // compute current tile
        short8 bfr[8], af[4];
#pragma unroll
        for (int fn = 0; fn < 8; ++fn) bfr[fn] = *(const short8*)(Wc + wfrag + fn * 1024);
#pragma unroll
        for (int fm = 0; fm < 4; ++fm) af[fm] = *(const short8*)(Ac + afrag + fm * 256);
#pragma unroll
        for (int fm = 0; fm < 4; ++fm)
#pragma unroll
            for (int fn = 0; fn < 8; ++fn)
                acc[fm][fn] = __builtin_amdgcn_mfma_f32_16x16x32_bf16(af[fm], bfr[fn], acc[fm][fn], 0, 0, 0);

        // finish A staging (vmcnt wait for a0/a1 lands here, after the MFMAs)
        if (kt < 15) {
            union { short8 s8; uint32_t u[4]; } uu;
            uu.u[0] = cvtpk_bf16(a0[0], a0[1]);
            uu.u[1] = cvtpk_bf16(a0[2], a0[3]);
            uu.u[2] = cvtpk_bf16(a1[0], a1[1]);
            uu.u[3] = cvtpk_bf16(a1[2], a1[3]);
            *(short8*)(An + aw_byte) = uu.s8;
        }
        __syncthreads();
    }

    // ---- epilogue overlays smem: sbuf [4][64] @0, pl [64] @1024, sb2 [4][512] @2048
    float* sbuf = (float*)smem;
    float* pl = (float*)(smem + 1024);
    float* sb2 = (float*)(smem + 2048);

    // epilogue 1: tanh(acc + dec_p) * V, reduce over a -> score partials
    float dpl[8], vl[8];
#pragma unroll
    for (int fn = 0; fn < 8; ++fn) {
        int a = w * 128 + fn * 16 + lrow;
        dpl[fn] = dp[b * NA + a];
        vl[fn] = V[a];
    }
    float ps[4][4];
#pragma unroll
    for (int fm = 0; fm < 4; ++fm)
#pragma unroll
        for (int i = 0; i < 4; ++i) ps[fm][i] = 0.f;

#pragma unroll
    for (int fm = 0; fm < 4; ++fm)
#pragma unroll
        for (int fn = 0; fn < 8; ++fn)
#pragma unroll
            for (int i = 0; i < 4; ++i) {
                float x = acc[fm][fn][i] + dpl[fn];
                float u = exp2f(x * 2.885390082f);           // tanh via exp2
                float th = 1.f - 2.f * __builtin_amdgcn_rcpf(u + 1.f);
                ps[fm][i] += th * vl[fn];
            }

#pragma unroll
    for (int fm = 0; fm < 4; ++fm)
#pragma unroll
        for (int i = 0; i < 4; ++i) {
            float v = ps[fm][i];
            v += __shfl_xor(v, 1);
            v += __shfl_xor(v, 2);
            v += __shfl_xor(v, 4);
            v += __shfl_xor(v, 8);
            if (lrow == 0) sbuf[w * 64 + fm * 16 + lg * 4 + i] = v;
        }
    __syncthreads();

    // epilogue 2: p = exp(score); no max needed (|score| <= sum|V| ~ 23, fp32-safe)
    if (tid < BM) {
        float s = sbuf[tid] + sbuf[64 + tid] + sbuf[128 + tid] + sbuf[192 + tid];
        float p = exp2f(s * 1.4426950408889634f);
        pl[tid] = p;
        pbuf[row0 + tid] = p;
    }
    __syncthreads();

    // epilogue 3: ctx partial = sum_s p_s * enc[s][:] (rows L2-hot from K-loop)
    // wave w owns s in [w*16, w*16+16); lane l owns h = l*8..l*8+8
    // store interleaved: c0 (h%8<4) at 16B-slot l, c1 at slot 64+l  -> 2-way banks
    f32x4 c0 = (f32x4){0.f, 0.f, 0.f, 0.f};
    f32x4 c1 = (f32x4){0.f, 0.f, 0.f, 0.f};
    const float* erow = enc + (size_t)(row0 + w * 16) * NH + l * 8;
#pragma unroll 4
    for (int s16 = 0; s16 < 16; ++s16) {
        float pw = pl[w * 16 + s16];
        f32x4 e0 = *(const f32x4*)(erow);
        f32x4 e1 = *(const f32x4*)(erow + 4);
        c0 += pw * e0;
        c1 += pw * e1;
        erow += NH;
    }
    {
        float* sw = sb2 + w * 512;
        *(f32x4*)(sw + l * 4) = c0;
        *(f32x4*)(sw + 256 + l * 4) = c1;
    }
    __syncthreads();

    // 256 threads x 2 h each: sum 4 waves, write ctx partial
    {
        int h2 = tid * 2;
        int q = h2 >> 3, r = h2 & 7;
        int idx = (r < 4) ? (q * 4 + r) : (256 + q * 4 + (r - 4));
        float r0 = sb2[idx] + sb2[512 + idx] + sb2[1024 + idx] + sb2[1536 + idx];
        float r1 = sb2[idx + 1] + sb2[512 + idx + 1] + sb2[1024 + idx + 1] + sb2[1536 + idx + 1];
        // idx maps h2 -> interleaved slot; (h2, h2+1) always within one 16B slot
        float2* dst = (float2*)(ctxp + (size_t)blockIdx.x * NH + h2);
        *dst = make_float2(r0, r1);
    }
}

// ---------------- kernel 3: combine partials -> out = [ctx | dec]
__global__ __launch_bounds__(256) void k_combine(const float* __restrict__ ctxp,
                                                 const float* __restrict__ pbuf,
                                                 const float* __restrict__ dec,
                                                 float* __restrict__ out) {
    int b = blockIdx.x;
    int tid = threadIdx.x;
    int l = tid & 63;
    int w = tid >> 6;
    __shared__ float red[4];
    __shared__ float stot;

    const f32x4* pv = (const f32x4*)(pbuf + (size_t)b * NS);
    f32x4 v0 = pv[tid * 2];
    f32x4 v1 = pv[tid * 2 + 1];
    float s = v0[0]+v0[1]+v0[2]+v0[3]+v1[0]+v1[1]+v1[2]+v1[3];
#pragma unroll
    for (int off = 1; off < 64; off <<= 1) s += __shfl_xor(s, off);
    if (l == 0) red[w] = s;
    __syncthreads();
    if (tid == 0) stot = red[0] + red[1] + red[2] + red[3];
    __syncthreads();
    float inv = 1.f / stot;

    int h2 = tid * 2;
    float a0 = 0.f, a1 = 0.f;
#pragma unroll 8
    for (int i = 0; i < NS / BM; ++i) {
        const float2 c = *(const float2*)(ctxp + ((size_t)b * (NS / BM) + i) * NH + h2);
        a0 += c.x;
        a1 += c.y;
    }
    *(float2*)(out + (size_t)b * 1024 + h2) = make_float2(a0 * inv, a1 * inv);
    const float2 dv = *(const float2*)(dec + (size_t)b * NH + h2);
    *(float2*)(out + (size_t)b * 1024 + NH + h2) = dv;
}

extern "C" void kernel_launch(void* const* d_in, const int* in_sizes, int n_in,
                              void* d_out, int out_size, void* d_ws, size_t ws_size,
                              hipStream_t stream) {
    (void)in_sizes; (void)n_in; (void)out_size; (void)ws_size;
    const float* dec = (const float*)d_in[0];
    const float* enc = (const float*)d_in[1];
    const float* Wd  = (const float*)d_in[2];
    const float* bd  = (const float*)d_in[3];
    const float* We  = (const float*)d_in[4];
    const float* be  = (const float*)d_in[5];
    const float* V   = (const float*)d_in[6];
    // d_in[7] (b_v) unused: cancels in softmax
    float* out = (float*)d_out;

    char* ws = (char*)d_ws;
    short* wsw    = (short*)ws;                         // 512 KB packed bf16 W
    float* dpb    = (float*)(ws + (512 << 10));         // 128 KB dec_p
    float* pbuf   = (float*)(ws + (640 << 10));         // 512 KB exp(scores)
    float* ctxp   = (float*)(ws + (1152 << 10));        // 4 MB ctx partials

    k_decp<<<dim3(NB), dim3(256), 0, stream>>>(dec, Wd, bd, be, dpb);
    k_packw<<<dim3(128), dim3(256), 0, stream>>>(We, wsw);
    k_fused<<<dim3((NB * NS) / BM), dim3(256), 0, stream>>>(enc, wsw, dpb, V, pbuf, ctxp);
    k_combine<<<dim3(NB), dim3(256), 0, stream>>>(ctxp, pbuf, dec, out);
}